// Round 14
// baseline (242.356 us; speedup 1.0000x reference)
//
#include <hip/hip_runtime.h>
#include <hip/hip_bf16.h>
#include <hip/hip_cooperative_groups.h>

namespace cg = cooperative_groups;

#define N_NODES 20000
#define N_EDGES 300000
#define FDIM    268
#define KPAD    288   // K padded to 9*32 for mfma K-loop
#define NPAD    288   // N padded to 9*32
#define MCOLS   256   // main h1 row (bf16), 64 slots of 4
#define TCOLS   16    // tail h1 row (bf16), 4 slots of 4 (12 valid + 4 zero)
#define ASTRIDE 296   // LDS A row stride in ushort (592B: 16B-aligned, 2-way bank worst case)
#define EPS     1e-3f
#define NB_SCAN ((N_NODES + 255) / 256)   // 79
#define CSR_BLOCKS 320

typedef __attribute__((ext_vector_type(8))) short short8;
typedef __attribute__((ext_vector_type(4))) float f32x4;
typedef __attribute__((ext_vector_type(4))) unsigned short ushort4_t;

__device__ inline unsigned short f2bf(float f) {
    __hip_bfloat16 b = __float2bfloat16(f);   // RNE
    return *reinterpret_cast<unsigned short*>(&b);
}
__device__ inline float bf2f(unsigned short u) {
    return __uint_as_float(((unsigned int)u) << 16);
}
__device__ inline int rdl_i(int v, int l)   { return __builtin_amdgcn_readlane(v, l); }
__device__ inline float rdl_f(float v, int l) {
    return __int_as_float(__builtin_amdgcn_readlane(__float_as_int(v), l));
}

// ---------------- CSR build: one cooperative kernel, 5 phases ----------------
__global__ __launch_bounds__(256) void csr_kernel(const int* __restrict__ row,
                                                  const int* __restrict__ col,
                                                  const float* __restrict__ W1,
                                                  unsigned short* __restrict__ wt,
                                                  int* __restrict__ counts,
                                                  int* __restrict__ offs,
                                                  int* __restrict__ cursor,
                                                  int* __restrict__ bsums,
                                                  float* __restrict__ dis,
                                                  int* __restrict__ esrc) {
    cg::grid_group grid = cg::this_grid();
    __shared__ int wsum[4];
    __shared__ int red[256];
    const int t = threadIdx.x;
    const int b = blockIdx.x;
    const int gtid = b * 256 + t;
    const int gstride = CSR_BLOCKS * 256;

    // phase 0: W1 -> W1^T bf16 padded; zero counts
    for (int idx = gtid; idx < NPAD * KPAD; idx += gstride) {
        int n = idx / KPAD, k = idx - n * KPAD;
        float v = (n < FDIM && k < FDIM) ? W1[(size_t)k * FDIM + n] : 0.f;
        wt[idx] = f2bf(v);
    }
    for (int i = gtid; i < N_NODES; i += gstride) counts[i] = 0;
    grid.sync();

    // phase 1: in-degree count
    for (int e = gtid; e < N_EDGES; e += gstride) atomicAdd(&counts[col[e]], 1);
    grid.sync();

    // phase 2: per-block exclusive scan (blocks 0..NB_SCAN-1); dis = rsqrt(deg+1)
    if (b < NB_SCAN) {
        int i = b * 256 + t;
        int c = (i < N_NODES) ? counts[i] : 0;
        int lane = t & 63, w = t >> 6;
        int v = c;
#pragma unroll
        for (int off = 1; off < 64; off <<= 1) {
            int u = __shfl_up(v, off);
            if (lane >= off) v += u;
        }
        if (lane == 63) wsum[w] = v;
        __syncthreads();
        int wbase = 0;
#pragma unroll
        for (int k = 0; k < 4; ++k) if (k < w) wbase += wsum[k];
        int incl = v + wbase;
        if (i < N_NODES) {
            offs[i] = incl - c;
            dis[i]  = rsqrtf((float)(c + 1));
        }
        if (t == 255) bsums[b] = incl;
    }
    grid.sync();

    // phase 3: add block bases; init cursor; total
    if (b < NB_SCAN) {
        red[t] = (t < NB_SCAN && t < b) ? bsums[t] : 0;
        __syncthreads();
#pragma unroll
        for (int st = 128; st > 0; st >>= 1) {
            if (t < st) red[t] += red[t + st];
            __syncthreads();
        }
        int base = red[0];
        int i = b * 256 + t;
        if (i < N_NODES) {
            int o = offs[i] + base;
            offs[i] = o;
            cursor[i] = o;
        }
        if (b == NB_SCAN - 1 && t == 0) offs[N_NODES] = base + bsums[b];
    }
    grid.sync();

    // phase 4: fill esrc by target
    for (int e = gtid; e < N_EDGES; e += gstride) {
        int c = col[e];
        int p = atomicAdd(&cursor[c], 1);
        esrc[p] = row[e];
    }
}

// ---------------- GEMM: bf16(x) @ wt -> h1main [N][256] + h1t [N][16] ----------------
// one block (512 thr = 8 waves) per 32-row m-strip; A staged f32->bf16 into LDS once;
// wave w owns n-tile w (wave 0 also does tile 8); 18 B-loads per tile fully unrolled.
__global__ __launch_bounds__(512) void gemm_mfma(const float* __restrict__ x,
                                                 const unsigned short* __restrict__ wt,
                                                 unsigned short* __restrict__ h1main,
                                                 unsigned short* __restrict__ h1t) {
    __shared__ unsigned short As[32 * ASTRIDE];   // 18,944 B
    const int tid = threadIdx.x;
    const int m0 = blockIdx.x * 32;

    // stage: 32 rows x 72 slots of 4 cols (268 = 67 full float4 slots; 67..71 -> zero pad)
    for (int c = tid; c < 32 * 72; c += 512) {
        int r = c / 72, s = c - r * 72;
        ushort4_t o;
        if (s < 67) {
            float4 v = *reinterpret_cast<const float4*>(x + (size_t)(m0 + r) * FDIM + s * 4);
            o[0] = f2bf(v.x); o[1] = f2bf(v.y); o[2] = f2bf(v.z); o[3] = f2bf(v.w);
        } else {
            o[0] = 0; o[1] = 0; o[2] = 0; o[3] = 0;
        }
        *reinterpret_cast<ushort4_t*>(&As[r * ASTRIDE + s * 4]) = o;
    }
    __syncthreads();

    const int lane = tid & 63;
    const int w    = tid >> 6;            // wave 0..7
    const int lrow = lane & 15;
    const int lkg  = lane >> 4;           // k-group 0..3
    const unsigned short* a_r0 = &As[lrow * ASTRIDE];
    const unsigned short* a_r1 = &As[(lrow + 16) * ASTRIDE];

    for (int nt = w; nt < 9; nt += 8) {   // wave 0: tiles {0,8}; waves 1..7: one tile
        const int n0 = nt * 32;
        f32x4 acc[2][2];
#pragma unroll
        for (int a = 0; a < 2; ++a)
#pragma unroll
            for (int b = 0; b < 2; ++b) acc[a][b] = (f32x4){0.f, 0.f, 0.f, 0.f};

        const unsigned short* wr0 = wt + (size_t)(n0 + lrow) * KPAD;
        const unsigned short* wr1 = wt + (size_t)(n0 + 16 + lrow) * KPAD;

#pragma unroll
        for (int k0 = 0; k0 < KPAD; k0 += 32) {
            const int kb = k0 + lkg * 8;
            short8 a0 = *reinterpret_cast<const short8*>(a_r0 + kb);
            short8 a1 = *reinterpret_cast<const short8*>(a_r1 + kb);
            short8 b0 = *reinterpret_cast<const short8*>(wr0 + kb);
            short8 b1 = *reinterpret_cast<const short8*>(wr1 + kb);
            acc[0][0] = __builtin_amdgcn_mfma_f32_16x16x32_bf16(a0, b0, acc[0][0], 0, 0, 0);
            acc[0][1] = __builtin_amdgcn_mfma_f32_16x16x32_bf16(a0, b1, acc[0][1], 0, 0, 0);
            acc[1][0] = __builtin_amdgcn_mfma_f32_16x16x32_bf16(a1, b0, acc[1][0], 0, 0, 0);
            acc[1][1] = __builtin_amdgcn_mfma_f32_16x16x32_bf16(a1, b1, acc[1][1], 0, 0, 0);
        }

        // C/D layout: col = lane&15, row = (lane>>4)*4 + reg   [m89-verified]
#pragma unroll
        for (int mi = 0; mi < 2; ++mi)
#pragma unroll
            for (int ni = 0; ni < 2; ++ni) {
                int colg = n0 + ni * 16 + lrow;
#pragma unroll
                for (int r = 0; r < 4; ++r) {
                    int rowg = m0 + mi * 16 + lkg * 4 + r;
                    unsigned short hv = f2bf(acc[mi][ni][r]);
                    if (colg < MCOLS) {
                        h1main[(size_t)rowg * MCOLS + colg] = hv;
                    } else if (colg < MCOLS + TCOLS) {
                        h1t[(size_t)rowg * TCOLS + (colg - MCOLS)] = hv;
                    }
                }
            }
    }
}

// ---------------- agg1: pull-aggregate + bias+relu+bn+relu + dot(W2) -> z ----------------
// grid-stride, one wave per node. Full-wave per edge row: lane l holds feats 4l..4l+3;
// 8 edges/iter, 8 row loads in flight. (src,w) broadcast via v_readlane (wave-uniform idx).
__global__ __launch_bounds__(256) void agg1_kernel(const unsigned short* __restrict__ h1main,
                                                   const unsigned short* __restrict__ h1t,
                                                   const int* __restrict__ offs,
                                                   const int* __restrict__ esrc,
                                                   const float* __restrict__ dis,
                                                   const float* __restrict__ b1,
                                                   const float* __restrict__ g1,
                                                   const float* __restrict__ beta1,
                                                   const float* __restrict__ rm1,
                                                   const float* __restrict__ rv1,
                                                   const float* __restrict__ W2,
                                                   float* __restrict__ z) {
    const int lane = threadIdx.x & 63;
    const int wave0 = blockIdx.x * 4 + (threadIdx.x >> 6);
    const int wstride = gridDim.x * 4;
    const ushort4_t* mbase = reinterpret_cast<const ushort4_t*>(h1main);  // row stride 64
    const ushort4_t* tbase = reinterpret_cast<const ushort4_t*>(h1t);    // row stride 4
    const int tsl = lane & 3;    // tail slot
    const int tei = lane >> 2;   // tail edge sub-index

    for (int i = wave0; i < N_NODES; i += wstride) {
        float a[4]  = {0.f, 0.f, 0.f, 0.f};
        float tb[4] = {0.f, 0.f, 0.f, 0.f};

        const int s = offs[i], e = offs[i + 1];
        const int deg = e - s;
        const float di = dis[i];

        // self-loop main: lane l -> slot l
        {
            ushort4_t v = mbase[(size_t)i * 64 + lane];
#pragma unroll
            for (int j = 0; j < 4; ++j) a[j] += di * bf2f(v[j]);
        }
        // self-loop tail: lanes 0..3 -> slots 0..3
        if (lane < 4) {
            ushort4_t v = tbase[(size_t)i * 4 + lane];
#pragma unroll
            for (int j = 0; j < 4; ++j) tb[j] += di * bf2f(v[j]);
        }

        for (int c0 = 0; c0 < deg; c0 += 64) {
            int cnt = deg - c0; if (cnt > 64) cnt = 64;
            int   lsrc = 0;
            float lw   = 0.f;
            if (lane < cnt) {
                lsrc = esrc[s + c0 + lane];    // coalesced
                lw   = dis[lsrc];
            }
            // ---- main: 8 edges/iter, 8 full-wave row loads in flight; pads add exact 0 ----
            const int niter = (cnt + 7) >> 3;
            for (int k = 0; k < niter; ++k) {
                int p = k * 8;
                int   s0 = rdl_i(lsrc, p),     s1 = rdl_i(lsrc, p + 1);
                int   s2 = rdl_i(lsrc, p + 2), s3 = rdl_i(lsrc, p + 3);
                int   s4 = rdl_i(lsrc, p + 4), s5 = rdl_i(lsrc, p + 5);
                int   s6 = rdl_i(lsrc, p + 6), s7 = rdl_i(lsrc, p + 7);
                float w0 = rdl_f(lw, p),       w1 = rdl_f(lw, p + 1);
                float w2 = rdl_f(lw, p + 2),   w3 = rdl_f(lw, p + 3);
                float w4 = rdl_f(lw, p + 4),   w5 = rdl_f(lw, p + 5);
                float w6 = rdl_f(lw, p + 6),   w7 = rdl_f(lw, p + 7);
                ushort4_t v0 = mbase[(size_t)s0 * 64 + lane];
                ushort4_t v1 = mbase[(size_t)s1 * 64 + lane];
                ushort4_t v2 = mbase[(size_t)s2 * 64 + lane];
                ushort4_t v3 = mbase[(size_t)s3 * 64 + lane];
                ushort4_t v4 = mbase[(size_t)s4 * 64 + lane];
                ushort4_t v5 = mbase[(size_t)s5 * 64 + lane];
                ushort4_t v6 = mbase[(size_t)s6 * 64 + lane];
                ushort4_t v7 = mbase[(size_t)s7 * 64 + lane];
#pragma unroll
                for (int j = 0; j < 4; ++j)
                    a[j] += w0 * bf2f(v0[j]) + w1 * bf2f(v1[j]) + w2 * bf2f(v2[j]) + w3 * bf2f(v3[j])
                          + w4 * bf2f(v4[j]) + w5 * bf2f(v5[j]) + w6 * bf2f(v6[j]) + w7 * bf2f(v7[j]);
            }
            // ---- tail: 16 edges/iter, lane l -> edge (l>>2), slot (l&3) ----
            const int tniter = (cnt + 15) >> 4;
            for (int k = 0; k < tniter; ++k) {
                int ei = k * 16 + tei;
                int   ts = __shfl(lsrc, ei);
                float tw = __shfl(lw, ei);
                ushort4_t v = tbase[(size_t)ts * 4 + tsl];
#pragma unroll
                for (int j = 0; j < 4; ++j) tb[j] += tw * bf2f(v[j]);
            }
        }

        // reduce tail across the 16 edge-groups (lanes sharing lane&3)
#pragma unroll
        for (int j = 0; j < 4; ++j) {
            tb[j] += __shfl_xor(tb[j], 4);
            tb[j] += __shfl_xor(tb[j], 8);
            tb[j] += __shfl_xor(tb[j], 16);
            tb[j] += __shfl_xor(tb[j], 32);
        }

        // epilogue: bias+relu+bn+relu+dot(W2). Main: lane l owns feats 4l..4l+3.
        float zp = 0.f;
        {
            int f0 = lane * 4;
#pragma unroll
            for (int j = 0; j < 4; ++j) {
                int f = f0 + j;
                float v = fmaxf(di * a[j] + b1[f], 0.f);
                v = fmaxf((v - rm1[f]) * rsqrtf(rv1[f] + EPS) * g1[f] + beta1[f], 0.f);
                zp += v * W2[f];
            }
        }
        if (lane < 3) {   // tail slots 0..2 = feats 256..267 exactly
            int f0 = 256 + lane * 4;
#pragma unroll
            for (int j = 0; j < 4; ++j) {
                int f = f0 + j;
                float v = fmaxf(di * tb[j] + b1[f], 0.f);
                v = fmaxf((v - rm1[f]) * rsqrtf(rv1[f] + EPS) * g1[f] + beta1[f], 0.f);
                zp += v * W2[f];
            }
        }
#pragma unroll
        for (int off = 32; off > 0; off >>= 1) zp += __shfl_xor(zp, off);
        if (lane == 0) z[i] = zp;
    }
}

// ---------------- agg2: 8 lanes per node; pull z + bias + bn + relu + sigmoid -> out ----------------
__global__ __launch_bounds__(256) void agg2_kernel(const float* __restrict__ z,
                                                   const int* __restrict__ offs,
                                                   const int* __restrict__ esrc,
                                                   const float* __restrict__ dis,
                                                   const float* __restrict__ b2,
                                                   const float* __restrict__ g2,
                                                   const float* __restrict__ beta2,
                                                   const float* __restrict__ rm2,
                                                   const float* __restrict__ rv2,
                                                   float* __restrict__ out) {
    int gt = blockIdx.x * blockDim.x + threadIdx.x;
    int i  = gt >> 3;          // node
    int l  = gt & 7;           // sub-lane 0..7
    if (i >= N_NODES) return;
    int s = offs[i], e = offs[i + 1];
    float acc = 0.f;
    for (int p = s + l; p < e; p += 8) {
        int s0 = esrc[p];
        acc += dis[s0] * z[s0];
    }
#pragma unroll
    for (int off = 1; off < 8; off <<= 1) acc += __shfl_xor(acc, off);
    if (l == 0) {
        float di = dis[i];
        acc += di * z[i];                 // self loop
        float pre = di * acc + b2[0];
        float v = (pre - rm2[0]) * rsqrtf(rv2[0] + EPS) * g2[0] + beta2[0];
        v = fmaxf(v, 0.f);
        out[i] = 1.f / (1.f + expf(-v));
    }
}

// ---------------- launcher ----------------
extern "C" void kernel_launch(void* const* d_in, const int* in_sizes, int n_in,
                              void* d_out, int out_size, void* d_ws, size_t ws_size,
                              hipStream_t stream) {
    const float* x     = (const float*)d_in[0];
    const int*   ei    = (const int*)d_in[1];     // [2, E]: row = ei, col = ei + E
    const float* W1    = (const float*)d_in[2];
    const float* b1    = (const float*)d_in[3];
    const float* g1    = (const float*)d_in[4];
    const float* beta1 = (const float*)d_in[5];
    const float* rm1   = (const float*)d_in[6];
    const float* rv1   = (const float*)d_in[7];
    const float* W2    = (const float*)d_in[8];
    const float* b2    = (const float*)d_in[9];
    const float* g2    = (const float*)d_in[10];
    const float* beta2 = (const float*)d_in[11];
    const float* rm2   = (const float*)d_in[12];
    const float* rv2   = (const float*)d_in[13];
    float* out = (float*)d_out;

    // workspace layout (~13 MB)
    unsigned short* wt     = (unsigned short*)d_ws;             // NPAD*KPAD
    unsigned short* h1main = wt + (size_t)NPAD * KPAD;          // N*256
    unsigned short* h1t    = h1main + (size_t)N_NODES * MCOLS;  // N*16
    float* z    = (float*)(h1t + (size_t)N_NODES * TCOLS);
    float* dis  = z + N_NODES;
    int* counts = (int*)(dis + N_NODES);
    int* offs   = counts + N_NODES;
    int* cursor = offs + N_NODES + 1;
    int* esrc   = cursor + N_NODES;
    int* bsums  = esrc + N_EDGES;                               // NB_SCAN

    const int* row = ei;
    const int* col = ei + N_EDGES;

    void* csr_args[] = {
        (void*)&row, (void*)&col, (void*)&W1, (void*)&wt, (void*)&counts,
        (void*)&offs, (void*)&cursor, (void*)&bsums, (void*)&dis, (void*)&esrc
    };
    hipLaunchCooperativeKernel((const void*)csr_kernel, dim3(CSR_BLOCKS), dim3(256),
                               csr_args, 0, stream);

    gemm_mfma<<<N_NODES / 32, 512, 0, stream>>>(x, wt, h1main, h1t);

    agg1_kernel<<<2048, 256, 0, stream>>>(h1main, h1t, offs, esrc, dis,
                                          b1, g1, beta1, rm1, rv1, W2, z);
    agg2_kernel<<<(N_NODES * 8 + 255) / 256, 256, 0, stream>>>(z, offs, esrc, dis,
                                                               b2, g2, beta2, rm2, rv2, out);
}

// Round 15
// 99.719 us; speedup vs baseline: 2.4304x; 2.4304x over previous
//
#include <hip/hip_runtime.h>
#include <hip/hip_bf16.h>

#define N_NODES 20000
#define N_EDGES 300000
#define FDIM    268
#define KPAD    288   // K padded to 9*32 for mfma K-loop
#define NPAD    288   // N padded to 9*32
#define MCOLS   256   // main h1 row (bf16), 64 slots of 4
#define TCOLS   16    // tail h1 row (bf16), 4 slots of 4 (12 valid + 4 zero)
#define ASTRIDE 296   // LDS A row stride in ushort (592B: 16B-aligned, 2-way bank worst case)
#define EPS     1e-3f
#define NB_SCAN ((N_NODES + 255) / 256)   // 79
#define NB_CONVW ((NPAD * KPAD + 255) / 256)  // 324

typedef __attribute__((ext_vector_type(8))) short short8;
typedef __attribute__((ext_vector_type(4))) float f32x4;
typedef __attribute__((ext_vector_type(4))) unsigned short ushort4_t;

__device__ inline unsigned short f2bf(float f) {
    __hip_bfloat16 b = __float2bfloat16(f);   // RNE
    return *reinterpret_cast<unsigned short*>(&b);
}
__device__ inline float bf2f(unsigned short u) {
    return __uint_as_float(((unsigned int)u) << 16);
}
__device__ inline int rdl_i(int v, int l)   { return __builtin_amdgcn_readlane(v, l); }
__device__ inline float rdl_f(float v, int l) {
    return __int_as_float(__builtin_amdgcn_readlane(__float_as_int(v), l));
}

// ---------------- prep: zero counts (blocks >= NB_CONVW) + W1 -> W1^T bf16 (blocks < NB_CONVW) ----------------
__global__ void prep_kernel(const float* __restrict__ W1, unsigned short* __restrict__ wt,
                            int* __restrict__ counts) {
    int b = blockIdx.x;
    if (b < NB_CONVW) {
        int idx = b * 256 + threadIdx.x;
        if (idx >= NPAD * KPAD) return;
        int n = idx / KPAD, k = idx - n * KPAD;
        float v = (n < FDIM && k < FDIM) ? W1[(size_t)k * FDIM + n] : 0.f;
        wt[idx] = f2bf(v);
    } else {
        int i = (b - NB_CONVW) * 256 + threadIdx.x;
        if (i < N_NODES) counts[i] = 0;
    }
}

__global__ void count_kernel(const int* __restrict__ col, int* __restrict__ counts) {
    int e = blockIdx.x * blockDim.x + threadIdx.x;
    if (e < N_EDGES) atomicAdd(&counts[col[e]], 1);
}

// stage 1: per-block exclusive scan (256 elems/block) -> offs (no base), block sums; dis
__global__ __launch_bounds__(256) void scan1_kernel(const int* __restrict__ counts,
                                                    int* __restrict__ offs,
                                                    int* __restrict__ bsums,
                                                    float* __restrict__ dis) {
    int t = threadIdx.x;
    int i = blockIdx.x * 256 + t;
    int c = (i < N_NODES) ? counts[i] : 0;
    int lane = t & 63, w = t >> 6;
    int v = c;
#pragma unroll
    for (int off = 1; off < 64; off <<= 1) {
        int u = __shfl_up(v, off);
        if (lane >= off) v += u;
    }
    __shared__ int wsum[4];
    if (lane == 63) wsum[w] = v;
    __syncthreads();
    int wbase = 0;
#pragma unroll
    for (int k = 0; k < 4; ++k) if (k < w) wbase += wsum[k];
    int incl = v + wbase;
    if (i < N_NODES) {
        offs[i] = incl - c;                         // block-local exclusive
        dis[i]  = rsqrtf((float)(c + 1));           // +1 self-loop
    }
    if (t == 255) bsums[blockIdx.x] = incl;         // block total (padding adds 0)
}

// stage 2 (merged): each block computes its own base from bsums, adds, inits cursor
__global__ __launch_bounds__(256) void scan3_kernel(const int* __restrict__ bsums,
                                                    int* __restrict__ offs,
                                                    int* __restrict__ cursor) {
    __shared__ int red[256];
    int t = threadIdx.x;
    int b = blockIdx.x;
    red[t] = (t < NB_SCAN && t < b) ? bsums[t] : 0;
    __syncthreads();
#pragma unroll
    for (int st = 128; st > 0; st >>= 1) {
        if (t < st) red[t] += red[t + st];
        __syncthreads();
    }
    int base = red[0];
    int i = b * 256 + t;
    if (i < N_NODES) {
        int o = offs[i] + base;
        offs[i] = o;
        cursor[i] = o;
    }
    if (b == NB_SCAN - 1 && t == 0) offs[N_NODES] = base + bsums[b];
}

__global__ void fill_kernel(const int* __restrict__ row, const int* __restrict__ col,
                            int* __restrict__ cursor, int* __restrict__ esrc) {
    int e = blockIdx.x * blockDim.x + threadIdx.x;
    if (e < N_EDGES) {
        int c = col[e];
        int p = atomicAdd(&cursor[c], 1);
        esrc[p] = row[e];
    }
}

// ---------------- GEMM: bf16(x) @ wt -> h1main [N][256] + h1t [N][16] ----------------
// one block (512 thr = 8 waves) per 32-row m-strip; A staged f32->bf16 into LDS once;
// wave w owns n-tile w (wave 0 also does tile 8); 18 B-loads per tile fully unrolled.
__global__ __launch_bounds__(512) void gemm_mfma(const float* __restrict__ x,
                                                 const unsigned short* __restrict__ wt,
                                                 unsigned short* __restrict__ h1main,
                                                 unsigned short* __restrict__ h1t) {
    __shared__ unsigned short As[32 * ASTRIDE];   // 18,944 B
    const int tid = threadIdx.x;
    const int m0 = blockIdx.x * 32;

    // stage: 32 rows x 72 slots of 4 cols (268 = 67 full float4 slots; 67..71 -> zero pad)
    for (int c = tid; c < 32 * 72; c += 512) {
        int r = c / 72, s = c - r * 72;
        ushort4_t o;
        if (s < 67) {
            float4 v = *reinterpret_cast<const float4*>(x + (size_t)(m0 + r) * FDIM + s * 4);
            o[0] = f2bf(v.x); o[1] = f2bf(v.y); o[2] = f2bf(v.z); o[3] = f2bf(v.w);
        } else {
            o[0] = 0; o[1] = 0; o[2] = 0; o[3] = 0;
        }
        *reinterpret_cast<ushort4_t*>(&As[r * ASTRIDE + s * 4]) = o;
    }
    __syncthreads();

    const int lane = tid & 63;
    const int w    = tid >> 6;            // wave 0..7
    const int lrow = lane & 15;
    const int lkg  = lane >> 4;           // k-group 0..3
    const unsigned short* a_r0 = &As[lrow * ASTRIDE];
    const unsigned short* a_r1 = &As[(lrow + 16) * ASTRIDE];

    for (int nt = w; nt < 9; nt += 8) {   // wave 0: tiles {0,8}; waves 1..7: one tile
        const int n0 = nt * 32;
        f32x4 acc[2][2];
#pragma unroll
        for (int a = 0; a < 2; ++a)
#pragma unroll
            for (int b = 0; b < 2; ++b) acc[a][b] = (f32x4){0.f, 0.f, 0.f, 0.f};

        const unsigned short* wr0 = wt + (size_t)(n0 + lrow) * KPAD;
        const unsigned short* wr1 = wt + (size_t)(n0 + 16 + lrow) * KPAD;

#pragma unroll
        for (int k0 = 0; k0 < KPAD; k0 += 32) {
            const int kb = k0 + lkg * 8;
            short8 a0 = *reinterpret_cast<const short8*>(a_r0 + kb);
            short8 a1 = *reinterpret_cast<const short8*>(a_r1 + kb);
            short8 b0 = *reinterpret_cast<const short8*>(wr0 + kb);
            short8 b1 = *reinterpret_cast<const short8*>(wr1 + kb);
            acc[0][0] = __builtin_amdgcn_mfma_f32_16x16x32_bf16(a0, b0, acc[0][0], 0, 0, 0);
            acc[0][1] = __builtin_amdgcn_mfma_f32_16x16x32_bf16(a0, b1, acc[0][1], 0, 0, 0);
            acc[1][0] = __builtin_amdgcn_mfma_f32_16x16x32_bf16(a1, b0, acc[1][0], 0, 0, 0);
            acc[1][1] = __builtin_amdgcn_mfma_f32_16x16x32_bf16(a1, b1, acc[1][1], 0, 0, 0);
        }

        // C/D layout: col = lane&15, row = (lane>>4)*4 + reg   [m89-verified]
#pragma unroll
        for (int mi = 0; mi < 2; ++mi)
#pragma unroll
            for (int ni = 0; ni < 2; ++ni) {
                int colg = n0 + ni * 16 + lrow;
#pragma unroll
                for (int r = 0; r < 4; ++r) {
                    int rowg = m0 + mi * 16 + lkg * 4 + r;
                    unsigned short hv = f2bf(acc[mi][ni][r]);
                    if (colg < MCOLS) {
                        h1main[(size_t)rowg * MCOLS + colg] = hv;
                    } else if (colg < MCOLS + TCOLS) {
                        h1t[(size_t)rowg * TCOLS + (colg - MCOLS)] = hv;
                    }
                }
            }
    }
}

// ---------------- agg1: pull-aggregate + bias+relu+bn+relu + dot(W2) -> z ----------------
// grid-stride, one wave per node. Full-wave per edge row: lane l holds feats 4l..4l+3;
// 8 edges/iter, 8 row loads in flight. (src,w) broadcast via v_readlane (wave-uniform idx).
__global__ __launch_bounds__(256) void agg1_kernel(const unsigned short* __restrict__ h1main,
                                                   const unsigned short* __restrict__ h1t,
                                                   const int* __restrict__ offs,
                                                   const int* __restrict__ esrc,
                                                   const float* __restrict__ dis,
                                                   const float* __restrict__ b1,
                                                   const float* __restrict__ g1,
                                                   const float* __restrict__ beta1,
                                                   const float* __restrict__ rm1,
                                                   const float* __restrict__ rv1,
                                                   const float* __restrict__ W2,
                                                   float* __restrict__ z) {
    const int lane = threadIdx.x & 63;
    const int wave0 = blockIdx.x * 4 + (threadIdx.x >> 6);
    const int wstride = gridDim.x * 4;
    const ushort4_t* mbase = reinterpret_cast<const ushort4_t*>(h1main);  // row stride 64
    const ushort4_t* tbase = reinterpret_cast<const ushort4_t*>(h1t);    // row stride 4
    const int tsl = lane & 3;    // tail slot
    const int tei = lane >> 2;   // tail edge sub-index

    for (int i = wave0; i < N_NODES; i += wstride) {
        float a[4]  = {0.f, 0.f, 0.f, 0.f};
        float tb[4] = {0.f, 0.f, 0.f, 0.f};

        const int s = offs[i], e = offs[i + 1];
        const int deg = e - s;
        const float di = dis[i];

        // self-loop main: lane l -> slot l
        {
            ushort4_t v = mbase[(size_t)i * 64 + lane];
#pragma unroll
            for (int j = 0; j < 4; ++j) a[j] += di * bf2f(v[j]);
        }
        // self-loop tail: lanes 0..3 -> slots 0..3
        if (lane < 4) {
            ushort4_t v = tbase[(size_t)i * 4 + lane];
#pragma unroll
            for (int j = 0; j < 4; ++j) tb[j] += di * bf2f(v[j]);
        }

        for (int c0 = 0; c0 < deg; c0 += 64) {
            int cnt = deg - c0; if (cnt > 64) cnt = 64;
            int   lsrc = 0;
            float lw   = 0.f;
            if (lane < cnt) {
                lsrc = esrc[s + c0 + lane];    // coalesced
                lw   = dis[lsrc];
            }
            // ---- main: 8 edges/iter, 8 full-wave row loads in flight; pads add exact 0 ----
            const int niter = (cnt + 7) >> 3;
            for (int k = 0; k < niter; ++k) {
                int p = k * 8;
                int   s0 = rdl_i(lsrc, p),     s1 = rdl_i(lsrc, p + 1);
                int   s2 = rdl_i(lsrc, p + 2), s3 = rdl_i(lsrc, p + 3);
                int   s4 = rdl_i(lsrc, p + 4), s5 = rdl_i(lsrc, p + 5);
                int   s6 = rdl_i(lsrc, p + 6), s7 = rdl_i(lsrc, p + 7);
                float w0 = rdl_f(lw, p),       w1 = rdl_f(lw, p + 1);
                float w2 = rdl_f(lw, p + 2),   w3 = rdl_f(lw, p + 3);
                float w4 = rdl_f(lw, p + 4),   w5 = rdl_f(lw, p + 5);
                float w6 = rdl_f(lw, p + 6),   w7 = rdl_f(lw, p + 7);
                ushort4_t v0 = mbase[(size_t)s0 * 64 + lane];
                ushort4_t v1 = mbase[(size_t)s1 * 64 + lane];
                ushort4_t v2 = mbase[(size_t)s2 * 64 + lane];
                ushort4_t v3 = mbase[(size_t)s3 * 64 + lane];
                ushort4_t v4 = mbase[(size_t)s4 * 64 + lane];
                ushort4_t v5 = mbase[(size_t)s5 * 64 + lane];
                ushort4_t v6 = mbase[(size_t)s6 * 64 + lane];
                ushort4_t v7 = mbase[(size_t)s7 * 64 + lane];
#pragma unroll
                for (int j = 0; j < 4; ++j)
                    a[j] += w0 * bf2f(v0[j]) + w1 * bf2f(v1[j]) + w2 * bf2f(v2[j]) + w3 * bf2f(v3[j])
                          + w4 * bf2f(v4[j]) + w5 * bf2f(v5[j]) + w6 * bf2f(v6[j]) + w7 * bf2f(v7[j]);
            }
            // ---- tail: 16 edges/iter, lane l -> edge (l>>2), slot (l&3) ----
            const int tniter = (cnt + 15) >> 4;
            for (int k = 0; k < tniter; ++k) {
                int ei = k * 16 + tei;
                int   ts = __shfl(lsrc, ei);
                float tw = __shfl(lw, ei);
                ushort4_t v = tbase[(size_t)ts * 4 + tsl];
#pragma unroll
                for (int j = 0; j < 4; ++j) tb[j] += tw * bf2f(v[j]);
            }
        }

        // reduce tail across the 16 edge-groups (lanes sharing lane&3)
#pragma unroll
        for (int j = 0; j < 4; ++j) {
            tb[j] += __shfl_xor(tb[j], 4);
            tb[j] += __shfl_xor(tb[j], 8);
            tb[j] += __shfl_xor(tb[j], 16);
            tb[j] += __shfl_xor(tb[j], 32);
        }

        // epilogue: bias+relu+bn+relu+dot(W2). Main: lane l owns feats 4l..4l+3.
        float zp = 0.f;
        {
            int f0 = lane * 4;
#pragma unroll
            for (int j = 0; j < 4; ++j) {
                int f = f0 + j;
                float v = fmaxf(di * a[j] + b1[f], 0.f);
                v = fmaxf((v - rm1[f]) * rsqrtf(rv1[f] + EPS) * g1[f] + beta1[f], 0.f);
                zp += v * W2[f];
            }
        }
        if (lane < 3) {   // tail slots 0..2 = feats 256..267 exactly
            int f0 = 256 + lane * 4;
#pragma unroll
            for (int j = 0; j < 4; ++j) {
                int f = f0 + j;
                float v = fmaxf(di * tb[j] + b1[f], 0.f);
                v = fmaxf((v - rm1[f]) * rsqrtf(rv1[f] + EPS) * g1[f] + beta1[f], 0.f);
                zp += v * W2[f];
            }
        }
#pragma unroll
        for (int off = 32; off > 0; off >>= 1) zp += __shfl_xor(zp, off);
        if (lane == 0) z[i] = zp;
    }
}

// ---------------- agg2: 8 lanes per node; pull z + bias + bn + relu + sigmoid -> out ----------------
__global__ __launch_bounds__(256) void agg2_kernel(const float* __restrict__ z,
                                                   const int* __restrict__ offs,
                                                   const int* __restrict__ esrc,
                                                   const float* __restrict__ dis,
                                                   const float* __restrict__ b2,
                                                   const float* __restrict__ g2,
                                                   const float* __restrict__ beta2,
                                                   const float* __restrict__ rm2,
                                                   const float* __restrict__ rv2,
                                                   float* __restrict__ out) {
    int gt = blockIdx.x * blockDim.x + threadIdx.x;
    int i  = gt >> 3;          // node
    int l  = gt & 7;           // sub-lane 0..7
    if (i >= N_NODES) return;
    int s = offs[i], e = offs[i + 1];
    float acc = 0.f;
    for (int p = s + l; p < e; p += 8) {
        int s0 = esrc[p];
        acc += dis[s0] * z[s0];
    }
#pragma unroll
    for (int off = 1; off < 8; off <<= 1) acc += __shfl_xor(acc, off);
    if (l == 0) {
        float di = dis[i];
        acc += di * z[i];                 // self loop
        float pre = di * acc + b2[0];
        float v = (pre - rm2[0]) * rsqrtf(rv2[0] + EPS) * g2[0] + beta2[0];
        v = fmaxf(v, 0.f);
        out[i] = 1.f / (1.f + expf(-v));
    }
}

// ---------------- launcher ----------------
extern "C" void kernel_launch(void* const* d_in, const int* in_sizes, int n_in,
                              void* d_out, int out_size, void* d_ws, size_t ws_size,
                              hipStream_t stream) {
    const float* x     = (const float*)d_in[0];
    const int*   ei    = (const int*)d_in[1];     // [2, E]: row = ei, col = ei + E
    const float* W1    = (const float*)d_in[2];
    const float* b1    = (const float*)d_in[3];
    const float* g1    = (const float*)d_in[4];
    const float* beta1 = (const float*)d_in[5];
    const float* rm1   = (const float*)d_in[6];
    const float* rv1   = (const float*)d_in[7];
    const float* W2    = (const float*)d_in[8];
    const float* b2    = (const float*)d_in[9];
    const float* g2    = (const float*)d_in[10];
    const float* beta2 = (const float*)d_in[11];
    const float* rm2   = (const float*)d_in[12];
    const float* rv2   = (const float*)d_in[13];
    float* out = (float*)d_out;

    // workspace layout (~13 MB)
    unsigned short* wt     = (unsigned short*)d_ws;             // NPAD*KPAD
    unsigned short* h1main = wt + (size_t)NPAD * KPAD;          // N*256
    unsigned short* h1t    = h1main + (size_t)N_NODES * MCOLS;  // N*16
    float* z    = (float*)(h1t + (size_t)N_NODES * TCOLS);
    float* dis  = z + N_NODES;
    int* counts = (int*)(dis + N_NODES);
    int* offs   = counts + N_NODES;
    int* cursor = offs + N_NODES + 1;
    int* esrc   = cursor + N_NODES;
    int* bsums  = esrc + N_EDGES;                               // NB_SCAN

    const int* row = ei;
    const int* col = ei + N_EDGES;

    int eb = (N_EDGES + 255) / 256;
    prep_kernel<<<NB_CONVW + NB_SCAN, 256, 0, stream>>>(W1, wt, counts);
    count_kernel<<<eb, 256, 0, stream>>>(col, counts);
    scan1_kernel<<<NB_SCAN, 256, 0, stream>>>(counts, offs, bsums, dis);
    scan3_kernel<<<NB_SCAN, 256, 0, stream>>>(bsums, offs, cursor);
    fill_kernel<<<eb, 256, 0, stream>>>(row, col, cursor, esrc);

    gemm_mfma<<<N_NODES / 32, 512, 0, stream>>>(x, wt, h1main, h1t);

    agg1_kernel<<<2048, 256, 0, stream>>>(h1main, h1t, offs, esrc, dis,
                                          b1, g1, beta1, rm1, rv1, W2, z);
    agg2_kernel<<<(N_NODES * 8 + 255) / 256, 256, 0, stream>>>(z, offs, esrc, dis,
                                                               b2, g2, beta2, rm2, rv2, out);
}